// Round 4
// baseline (257.604 us; speedup 1.0000x reference)
//
#include <hip/hip_runtime.h>
#include <hip/hip_bf16.h>
#include <math.h>

#define HC 64
#define DD 128
#define BSH 7       // bucket = 128 consecutive ids
#define BW  128
#define KMAX 512    // max buckets; ids must fit 16 bits (N <= 65536)
#define CHUNK 4096  // edges per partition/hist workgroup
#define CAP 8192    // LDS sort capacity in bucket_csr (entries)

typedef __attribute__((ext_vector_type(8))) short bf16x8;
typedef __attribute__((ext_vector_type(4))) float f32x4;

// round-to-nearest-even f32 -> bf16 bits (inputs finite)
__device__ __forceinline__ unsigned short f2bf(float f) {
  unsigned u = __float_as_uint(f);
  return (unsigned short)((u + 0x7fffu + ((u >> 16) & 1u)) >> 16);
}

// ---------------- build folded B matrix [80][128] bf16 ----------------
// cols (rows of Bt) 0..63 : Wsrc^T
// 64: sum_c Wsrc[k][ 0+c]*att_src[ 0+c]*LOG2E   (ls head0)
// 65: sum_c Wsrc[k][32+c]*att_src[32+c]*LOG2E   (ls head1)
// 66: sum_c Wdst[k][ 0+c]*att_dst[ 0+c]*LOG2E   (ld head0)
// 67: sum_c Wdst[k][32+c]*att_dst[32+c]*LOG2E   (ld head1)
// 68..79: zero pad (5 MFMA col-tiles of 16)
__global__ __launch_bounds__(128) void build_bt(
    const float* __restrict__ Wsrc, const float* __restrict__ Wdst,
    const float* __restrict__ att_src, const float* __restrict__ att_dst,
    unsigned short* __restrict__ Bt)
{
  int j = blockIdx.x;      // 0..79
  int k = threadIdx.x;     // 0..127
  const float LOG2E = 1.44269504f;
  float v = 0.f;
  if (j < 64) {
    v = Wsrc[k * HC + j];
  } else if (j < 68) {
    int hh = j - 64;
    const float* W = (hh < 2) ? Wsrc : Wdst;
    const float* a = (hh < 2) ? att_src : att_dst;
    int h = hh & 1;
    float s = 0.f;
    for (int c = 0; c < 32; ++c)
      s = fmaf(W[k * HC + h * 32 + c], a[h * 32 + c], s);
    v = s * LOG2E;
  }
  Bt[j * DD + k] = f2bf(v);
}

// ---------------- node transform via MFMA (both graphs, one grid) ------
// one wave = 16 nodes. A = elu(x) split hi/lo bf16 (error ~= W rounding only).
__global__ __launch_bounds__(256) void node_mfma(
    const float* __restrict__ xH, const float* __restrict__ xT,
    const unsigned short* __restrict__ Bt,
    __hip_bfloat16* __restrict__ xsH, __hip_bfloat16* __restrict__ xsT,
    float* __restrict__ lsH, float* __restrict__ ldH,
    float* __restrict__ lsT, float* __restrict__ ldT,
    int NH, int NT, int blocksH)
{
  const float* x; __hip_bfloat16* xs; float* logit_s; float* logit_d; int N, blk;
  if ((int)blockIdx.x < blocksH) { x = xH; xs = xsH; logit_s = lsH; logit_d = ldH; N = NH; blk = blockIdx.x; }
  else { x = xT; xs = xsT; logit_s = lsT; logit_d = ldT; N = NT; blk = blockIdx.x - blocksH; }

  int tid  = threadIdx.x;
  int wid  = tid >> 6;
  int lane = tid & 63;
  int m    = lane & 15;          // A row / D col index
  int kg   = lane >> 4;          // k-group 0..3
  int nbase = (blk * 4 + wid) * 16;
  if (nbase >= N) return;
  int nrow = nbase + m;
  int nclamp = (nrow < N) ? nrow : (N - 1);

  // ---- load A (4 k-tiles x 8 f32), elu, hi/lo bf16 split ----
  bf16x8 ahi[4], alo[4];
  const float* xrow = x + (size_t)nclamp * DD + kg * 8;
  #pragma unroll
  for (int kt = 0; kt < 4; ++kt) {
    float4 v0 = *(const float4*)(xrow + kt * 32);
    float4 v1 = *(const float4*)(xrow + kt * 32 + 4);
    float vv[8] = {v0.x, v0.y, v0.z, v0.w, v1.x, v1.y, v1.z, v1.w};
    #pragma unroll
    for (int i = 0; i < 8; ++i) {
      float v = vv[i];
      v = (v > 0.f) ? v : (exp2f(v * 1.44269504f) - 1.f);   // elu
      unsigned hb = __float_as_uint(v) & 0xffff0000u;       // truncate -> hi
      ahi[kt][i] = (short)(hb >> 16);
      alo[kt][i] = (short)f2bf(v - __uint_as_float(hb));    // exact residual, RNE
    }
  }

  // ---- MFMA: 5 col-tiles x 4 k-tiles x (hi+lo) ----
  f32x4 acc[5];
  #pragma unroll
  for (int ct = 0; ct < 5; ++ct) acc[ct] = (f32x4){0.f, 0.f, 0.f, 0.f};
  const unsigned short* bbase = Bt + m * DD + kg * 8;   // + ct*16*DD + kt*32
  #pragma unroll
  for (int ct = 0; ct < 5; ++ct) {
    #pragma unroll
    for (int kt = 0; kt < 4; ++kt) {
      bf16x8 b = *(const bf16x8*)(bbase + ct * 16 * DD + kt * 32);
      acc[ct] = __builtin_amdgcn_mfma_f32_16x16x32_bf16(ahi[kt], b, acc[ct], 0, 0, 0);
      acc[ct] = __builtin_amdgcn_mfma_f32_16x16x32_bf16(alo[kt], b, acc[ct], 0, 0, 0);
    }
  }

  // ---- epilogue ----
  int r0 = kg * 4;
  unsigned short* xsu = (unsigned short*)xs;
  #pragma unroll
  for (int ct = 0; ct < 4; ++ct) {
    #pragma unroll
    for (int r = 0; r < 4; ++r) {
      int n = nbase + r0 + r;
      if (n < N) xsu[(size_t)n * HC + ct * 16 + m] = f2bf(acc[ct][r]);
    }
  }
  if (m < 4) {
    float* dst = (m < 2) ? logit_s : logit_d;
    int h = m & 1;
    #pragma unroll
    for (int r = 0; r < 4; ++r) {
      int n = nbase + r0 + r;
      if (n < N) dst[n * 2 + h] = acc[4][r];
    }
  }
}

// ---------------- counting sort ----------------
__global__ __launch_bounds__(256) void hist_both(
    const int* __restrict__ src, const int* __restrict__ dst, int E, int NL,
    int* __restrict__ histA, int* __restrict__ histB, int KA, int KB, int B)
{
  __shared__ int hA[KMAX];
  __shared__ int hB[KMAX];
  int tid = threadIdx.x, bid = blockIdx.x;
  for (int i = tid; i < KA; i += 256) hA[i] = 0;
  for (int i = tid; i < KB; i += 256) hB[i] = 0;
  __syncthreads();
  int base = bid * CHUNK;
  int E2 = E + NL;
  int lim = base + CHUNK < E2 ? base + CHUNK : E2;
  for (int i = base + tid; i < lim; i += 256) {
    int s, d;
    if (i < E) { s = src[i]; d = dst[i]; } else { s = d = i - E; }
    atomicAdd(&hA[d >> BSH], 1);
    atomicAdd(&hB[s >> BSH], 1);
  }
  __syncthreads();
  for (int k = tid; k < KA; k += 256) histA[(size_t)k * B + bid] = hA[k];
  for (int k = tid; k < KB; k += 256) histB[(size_t)k * B + bid] = hB[k];
}

// one WAVE per bucket: exclusive scan of its B chunk counts; emit totals
__global__ __launch_bounds__(256) void scan_hist(
    int* __restrict__ histA, int KA, int* __restrict__ histB, int KB, int B,
    int* __restrict__ totals)
{
  int j = blockIdx.x * 4 + (threadIdx.x >> 6);
  if (j >= KA + KB) return;
  int lane = threadIdx.x & 63;
  int* rowp = (j < KA) ? &histA[(size_t)j * B] : &histB[(size_t)(j - KA) * B];
  int carry = 0;
  for (int c0 = 0; c0 < B; c0 += 64) {
    int c = c0 + lane;
    int v = (c < B) ? rowp[c] : 0;
    int inc = v;
    #pragma unroll
    for (int off = 1; off < 64; off <<= 1) {
      int u = __shfl_up(inc, off, 64);
      if (lane >= off) inc += u;
    }
    if (c < B) rowp[c] = inc - v + carry;
    carry += __shfl(inc, 63, 64);
  }
  if (lane == 0) totals[j] = carry;
}

__global__ __launch_bounds__(1024) void scan_totals(
    const int* __restrict__ totals, int KA, int KB, int E2,
    int* __restrict__ offA, int* __restrict__ offB)
{
  __shared__ int buf[1024];
  int t = threadIdx.x;
  int v = (t < KA) ? totals[t] : 0;
  buf[t] = v; __syncthreads();
  #pragma unroll
  for (int off = 1; off < 1024; off <<= 1) {
    int u = (t >= off) ? buf[t - off] : 0;
    __syncthreads(); buf[t] += u; __syncthreads();
  }
  if (t < KA) offA[t] = buf[t] - v;
  if (t == 0) offA[KA] = E2;
  __syncthreads();
  int v2 = (t < KB) ? totals[KA + t] : 0;
  buf[t] = v2; __syncthreads();
  #pragma unroll
  for (int off = 1; off < 1024; off <<= 1) {
    int u = (t >= off) ? buf[t - off] : 0;
    __syncthreads(); buf[t] += u; __syncthreads();
  }
  if (t < KB) offB[t] = buf[t] - v2;
  if (t == 0) offB[KB] = E2;
}

// partition into bucket-contiguous segments. word = other | (key << 16);
// bucket recovered as w >> (16+BSH) (no search). blockIdx.y selects pass.
__global__ __launch_bounds__(256) void partition_edges(
    const int* __restrict__ src, const int* __restrict__ dst, int E, int NL,
    const int* __restrict__ histA, const int* __restrict__ offA,
    const int* __restrict__ histB, const int* __restrict__ offB,
    unsigned int* __restrict__ partA, unsigned int* __restrict__ partB,
    int KA, int KB, int B)
{
  __shared__ unsigned int stage[CHUNK];  // 16 KB
  __shared__ int lbase[KMAX];
  __shared__ int lcur[KMAX];
  __shared__ int gbase[KMAX];
  int tid = threadIdx.x, bid = blockIdx.x;
  int pass = blockIdx.y;
  const int K = pass ? KB : KA;
  const int* hist = pass ? histB : histA;
  const int* off  = pass ? offB : offA;
  unsigned int* out = pass ? partB : partA;

  int base = bid * CHUNK;
  int E2 = E + NL;
  int lim = base + CHUNK < E2 ? base + CHUNK : E2;
  int cnt = lim - base;

  for (int i = tid; i < K; i += 256) lbase[i] = 0;
  __syncthreads();
  for (int i = base + tid; i < lim; i += 256) {
    int s, d;
    if (i < E) { s = src[i]; d = dst[i]; } else { s = d = i - E; }
    int key = pass ? s : d;
    atomicAdd(&lbase[key >> BSH], 1);
  }
  __syncthreads();
  if (tid < 64) {                      // wave-0 exclusive scan over K counts
    int carry = 0;
    for (int c0 = 0; c0 < K; c0 += 64) {
      int c = c0 + tid;
      int v = (c < K) ? lbase[c] : 0;
      int inc = v;
      #pragma unroll
      for (int o = 1; o < 64; o <<= 1) {
        int u = __shfl_up(inc, o, 64);
        if (tid >= o) inc += u;
      }
      if (c < K) lbase[c] = inc - v + carry;
      carry += __shfl(inc, 63, 64);
    }
  }
  __syncthreads();
  for (int k = tid; k < K; k += 256) {
    lcur[k] = lbase[k];
    gbase[k] = off[k] + hist[(size_t)k * B + bid];
  }
  __syncthreads();
  for (int i = base + tid; i < lim; i += 256) {
    int s, d;
    if (i < E) { s = src[i]; d = dst[i]; } else { s = d = i - E; }
    int key = pass ? s : d;
    int val = pass ? d : s;
    int pos = atomicAdd(&lcur[key >> BSH], 1);
    stage[pos] = (unsigned int)val | ((unsigned int)key << 16);
  }
  __syncthreads();
  for (int i = tid; i < cnt; i += 256) {
    unsigned int wv = stage[i];
    int k = wv >> (16 + BSH);
    out[gbase[k] + (i - lbase[k])] = wv;
  }
}

// per-bucket key-sort in LDS -> csr (coalesced write) + row pointers; both passes
__global__ __launch_bounds__(256) void bucket_csr2(
    const unsigned int* __restrict__ partA, const int* __restrict__ offA, int KA, int NA,
    const unsigned int* __restrict__ partB, const int* __restrict__ offB, int KB, int NB,
    int E2, int* __restrict__ csrA, int* __restrict__ rowA,
    int* __restrict__ csrB, int* __restrict__ rowB)
{
  __shared__ int sbuf[CAP];        // 32 KB
  __shared__ int hist[BW + 1];
  __shared__ int cur[BW];
  const unsigned int* part; const int* off; int* csr; int* row; int k, K, N;
  if ((int)blockIdx.x < KA) { k = blockIdx.x; part = partA; off = offA; csr = csrA; row = rowA; K = KA; N = NA; }
  else { k = blockIdx.x - KA; part = partB; off = offB; csr = csrB; row = rowB; K = KB; N = NB; }
  int tid = threadIdx.x;
  int beg = off[k], end = off[k + 1];
  int d0 = k << BSH;
  int width = (BW < N - d0) ? BW : (N - d0);
  int cnt = end - beg;

  for (int i = tid; i <= BW; i += 256) hist[i] = 0;
  __syncthreads();
  for (int i = tid; i < cnt; i += 256)
    atomicAdd(&hist[(part[beg + i] >> 16) & (BW - 1)], 1);
  __syncthreads();
  if (tid == 0) {
    int run = 0;
    for (int j = 0; j < width; ++j) { int c = hist[j]; hist[j] = run; run += c; }
    hist[width] = run;
  }
  __syncthreads();
  if (tid < width) { cur[tid] = hist[tid]; row[d0 + tid] = beg + hist[tid]; }
  if (k == K - 1 && tid == 0) row[N] = E2;
  __syncthreads();
  if (cnt <= CAP) {
    for (int i = tid; i < cnt; i += 256) {
      unsigned int wv = part[beg + i];
      int pos = atomicAdd(&cur[(wv >> 16) & (BW - 1)], 1);
      sbuf[pos] = wv & 0xFFFF;
    }
    __syncthreads();
    for (int i = tid; i < cnt; i += 256) csr[beg + i] = sbuf[i];
  } else {
    for (int i = tid; i < cnt; i += 256) {   // fallback, never for uniform data
      unsigned int wv = part[beg + i];
      int pos = atomicAdd(&cur[(wv >> 16) & (BW - 1)], 1);
      csr[beg + pos] = wv & 0xFFFF;
    }
  }
}

// ---------------- message stage ----------------
__device__ __forceinline__ float lrelu_clamp(float a) {
  a = (a > 0.f) ? a : 0.2f * a;
  return fminf(a, 43.f);
}

// csr_message6: 2 dsts/wave (half-wave each), 2 channels/lane, 64-edge rounds.
// Per round, ONE preamble fills 64 weight slots for BOTH dsts (two
// independent load chains overlap): all 64 lanes compute dst0's edges
// 0..63, then dst1's, into bank-staggered 64-entry LDS arrays. After the
// sv loads, each lane issues 2 touch loads at its edge's xs row to warm
// L2 (rows are 128B-aligned) - kept alive by an empty asm at round end.
// Inner loop: 2-quad unrolled ds_read_b128 broadcasts (conflict-free) +
// saddr-form dword gathers; qmax rounded to even (slots zero-filled so
// over-run adds exact zeros). deg~33 => nrounds=1, one preamble / 2 dsts.
__global__ __launch_bounds__(256) void csr_message6(
    const int* __restrict__ rowA, const int* __restrict__ csrA,
    const float* __restrict__ lsA, const float* __restrict__ ldA,
    const __hip_bfloat16* __restrict__ xsA, float* __restrict__ outA, int NdA,
    const int* __restrict__ rowB, const int* __restrict__ csrB,
    const float* __restrict__ lsB, const float* __restrict__ ldB,
    const __hip_bfloat16* __restrict__ xsB, float* __restrict__ outB, int NdB,
    const float* __restrict__ bias, int blocksA)
{
  const int* row; const int* csr_src; const float* logit_s; const float* logit_d;
  const __hip_bfloat16* xs; float* out; int Nd, blk;
  if ((int)blockIdx.x < blocksA) { row = rowA; csr_src = csrA; logit_s = lsA; logit_d = ldA; xs = xsA; out = outA; Nd = NdA; blk = blockIdx.x; }
  else { row = rowB; csr_src = csrB; logit_s = lsB; logit_d = ldB; xs = xsB; out = outB; Nd = NdB; blk = blockIdx.x - blocksA; }

  // per-wave strip: 432 words; array bases (word, base mod 32 banks):
  //   sv0 @   0 (0)    sv1 @  72 (8)
  //   w00 @ 144 (16)   w10 @ 216 (24)    [dst0: head0, head1]
  //   w01 @ 288 (0)    w11 @ 360 (8)     [dst1: head0, head1]
  // quad reads: svq 2 addrs spans {4q,4q+3}+{0,8}; wq 4 addrs +{16,24,0,8} - disjoint
  __shared__ int lds[4 * 432];   // 6912 B
  int tid  = threadIdx.x;
  int wid  = tid >> 6;
  int lane = tid & 63;
  int l31  = lane & 31;
  int half = lane >> 5;
  int head = l31 >> 4;

  int* L = &lds[wid * 432];
  float* Lf = (float*)L;
  const int4*   svq = (const int4*)  (L  + (half ? 72 : 0));
  const float4* wq  = (const float4*)(Lf + (half ? (head ? 360 : 288)
                                                 : (head ? 216 : 144)));
  const unsigned* xs2 = (const unsigned*)xs;     // bf16 pair per dword
  const float2* ls2 = (const float2*)logit_s;

  int d0 = blk * 8 + (wid << 1);
  if (d0 >= Nd) return;                 // per-wave exit; no block barriers used
  int d1 = d0 + 1;
  int has1 = (d1 < Nd);

  int b0 = row[d0];
  int m0 = row[d0 + 1];
  int m1 = has1 ? row[d1 + 1] : m0;
  float2 ld20 = ((const float2*)logit_d)[d0];
  float2 ld21 = has1 ? ((const float2*)logit_d)[d1] : (float2){0.f, 0.f};

  int deg0 = m0 - b0;
  int deg1 = m1 - m0;
  int dmax = max(deg0, deg1);
  int nrounds = (dmax + 63) >> 6;

  float2 accA = {0.f, 0.f}, accB = {0.f, 0.f};
  float s00 = 0.f, s10 = 0.f, s01 = 0.f, s11 = 0.f;   // s[head][dst]

#define STEP(SV, W, ACC) {                                         \
    unsigned xv = xs2[(unsigned)(SV) * 32u + (unsigned)l31];       \
    ACC.x = fmaf((W), __uint_as_float(xv << 16), ACC.x);           \
    ACC.y = fmaf((W), __uint_as_float(xv & 0xffff0000u), ACC.y);   \
  }

  for (int r = 0; r < nrounds; ++r) {
    int base = r << 6;
    // ---- preamble: fill 64 slots for dst0 and dst1 (chains overlap) ----
    int i0 = b0 + base + lane;
    int sv0 = 0; float e00 = 0.f, e10 = 0.f;
    if (i0 < m0) {
      sv0 = csr_src[i0];
      float2 l2 = ls2[sv0];
      e00 = exp2f(lrelu_clamp(l2.x + ld20.x));
      e10 = exp2f(lrelu_clamp(l2.y + ld20.y));
    }
    int i1 = m0 + base + lane;
    int sv1 = 0; float e01 = 0.f, e11 = 0.f;
    if (i1 < m1) {
      sv1 = csr_src[i1];
      float2 l2 = ls2[sv1];
      e01 = exp2f(lrelu_clamp(l2.x + ld21.x));
      e11 = exp2f(lrelu_clamp(l2.y + ld21.y));
    }
    s00 += e00; s10 += e10; s01 += e01; s11 += e11;

    // L2 touch-prefetch of this round's xs rows (128B row = 2x64B lines)
    unsigned t0 = xs2[(unsigned)sv0 * 32u];
    unsigned t1 = xs2[(unsigned)sv0 * 32u + 16u];
    unsigned t2 = xs2[(unsigned)sv1 * 32u];
    unsigned t3 = xs2[(unsigned)sv1 * 32u + 16u];

    L[lane]        = sv0;
    L[72 + lane]   = sv1;
    Lf[144 + lane] = e00;
    Lf[216 + lane] = e10;
    Lf[288 + lane] = e01;
    Lf[360 + lane] = e11;
    // same-wave cross-lane LDS RAW: DS ops in-order per wave; drain writes
    asm volatile("s_waitcnt lgkmcnt(0)" ::: "memory");

    int tc0 = deg0 - base; tc0 = tc0 < 0 ? 0 : (tc0 > 64 ? 64 : tc0);
    int tc1 = deg1 - base; tc1 = tc1 < 0 ? 0 : (tc1 > 64 ? 64 : tc1);
    int qmax = (max(tc0, tc1) + 3) >> 2;
    qmax = (qmax + 1) & ~1;            // even: 2-quad unroll, zero-padded slots
    for (int q = 0; q < qmax; q += 2) {
      int4   s4a = svq[q],     s4b = svq[q + 1];
      float4 w4a = wq[q],      w4b = wq[q + 1];
      STEP(s4a.x, w4a.x, accA)
      STEP(s4a.y, w4a.y, accB)
      STEP(s4a.z, w4a.z, accA)
      STEP(s4a.w, w4a.w, accB)
      STEP(s4b.x, w4b.x, accA)
      STEP(s4b.y, w4b.y, accB)
      STEP(s4b.z, w4b.z, accA)
      STEP(s4b.w, w4b.w, accB)
    }
    // keep touch loads alive (waits here, after the inner loop - free)
    asm volatile("" :: "v"(t0), "v"(t1), "v"(t2), "v"(t3));
  }
#undef STEP

  // denominators: full-wave reduce each of the 4 sums
  #pragma unroll
  for (int off = 32; off > 0; off >>= 1) {
    s00 += __shfl_xor(s00, off, 64);
    s10 += __shfl_xor(s10, off, 64);
    s01 += __shfl_xor(s01, off, 64);
    s11 += __shfl_xor(s11, off, 64);
  }
  float sD = half ? (head ? s11 : s01) : (head ? s10 : s00);
  float inv = 1.f / (sD + 1e-16f);

  if (half == 0 || has1) {
    int d = half ? d1 : d0;
    float2 b2 = ((const float2*)bias)[l31];
    float2 o;
    o.x = (accA.x + accB.x) * inv + b2.x;
    o.y = (accA.y + accB.y) * inv + b2.y;
    ((float2*)out)[(size_t)d * 32 + l31] = o;
  }
}

extern "C" void kernel_launch(void* const* d_in, const int* in_sizes, int n_in,
                              void* d_out, int out_size, void* d_ws, size_t ws_size,
                              hipStream_t stream)
{
  const float* h_x   = (const float*)d_in[0];
  const float* t_x   = (const float*)d_in[1];
  const int*   edge  = (const int*)d_in[2];
  const float* W_src = (const float*)d_in[3];
  const float* W_dst = (const float*)d_in[4];
  const float* att_s = (const float*)d_in[5];
  const float* att_d = (const float*)d_in[6];
  const float* bias  = (const float*)d_in[7];

  int NH = in_sizes[0] / DD;
  int NT = in_sizes[1] / DD;
  int E  = in_sizes[2] / 2;
  int NL = (NH < NT) ? NH : NT;
  int E2 = E + NL;
  const int* srcA = edge;       // row 0 (h index)
  const int* dstA = edge + E;   // row 1 (t index)

  int KA = (NT + BW - 1) >> BSH;   // pass A buckets (over t / dst)
  int KB = (NH + BW - 1) >> BSH;   // pass B buckets (over h / src)
  int B  = (E2 + CHUNK - 1) / CHUNK;

  char* w = (char*)d_ws;
  size_t used = 0;
  auto alloc = [&](size_t bytes) {
    char* p = w + used; used = (used + bytes + 255) & ~(size_t)255; return p;
  };
  __hip_bfloat16* xsA = (__hip_bfloat16*)alloc((size_t)NH * HC * 2);
  __hip_bfloat16* xsB = (__hip_bfloat16*)alloc((size_t)NT * HC * 2);
  float* lsA  = (float*)alloc((size_t)NH * 2 * 4);
  float* ldB  = (float*)alloc((size_t)NH * 2 * 4);
  float* lsB  = (float*)alloc((size_t)NT * 2 * 4);
  float* ldA  = (float*)alloc((size_t)NT * 2 * 4);
  int* histA  = (int*)alloc((size_t)KA * B * 4);
  int* histB  = (int*)alloc((size_t)KB * B * 4);
  int* totals = (int*)alloc((size_t)(KA + KB) * 4);
  int* offA   = (int*)alloc((size_t)(KA + 1) * 4);
  int* offB   = (int*)alloc((size_t)(KB + 1) * 4);
  int* rowT   = (int*)alloc((size_t)(NT + 1) * 4);
  int* rowH   = (int*)alloc((size_t)(NH + 1) * 4);
  unsigned int* partA = (unsigned int*)alloc((size_t)E2 * 4);
  unsigned int* partB = (unsigned int*)alloc((size_t)E2 * 4);
  int* csrT   = (int*)alloc((size_t)E2 * 4);
  int* csrH   = (int*)alloc((size_t)E2 * 4);
  unsigned short* Bt = (unsigned short*)alloc((size_t)80 * DD * 2);

  float* out   = (float*)d_out;              // (h_rep [NH,64], t_rep [NT,64])
  float* out_h = out;
  float* out_t = out + (size_t)NH * HC;

  build_bt<<<80, 128, 0, stream>>>(W_src, W_dst, att_s, att_d, Bt);

  int bH = (NH + 63) / 64, bT = (NT + 63) / 64;
  node_mfma<<<bH + bT, 256, 0, stream>>>(
      h_x, t_x, Bt, xsA, xsB, lsA, ldB, lsB, ldA, NH, NT, bH);

  hist_both<<<B, 256, 0, stream>>>(srcA, dstA, E, NL, histA, histB, KA, KB, B);
  scan_hist<<<(KA + KB + 3) / 4, 256, 0, stream>>>(histA, KA, histB, KB, B, totals);
  scan_totals<<<1, 1024, 0, stream>>>(totals, KA, KB, E2, offA, offB);
  partition_edges<<<dim3(B, 2), 256, 0, stream>>>(
      srcA, dstA, E, NL, histA, offA, histB, offB, partA, partB, KA, KB, B);
  bucket_csr2<<<KA + KB, 256, 0, stream>>>(partA, offA, KA, NT, partB, offB, KB, NH,
                                           E2, csrT, rowT, csrH, rowH);

  // pass A: src=h, dst=t -> t_rep ; pass B: src=t, dst=h -> h_rep
  // 8 dsts per block (4 waves x 2 dsts/wave)
  int gA = (NT + 7) / 8, gB = (NH + 7) / 8;
  csr_message6<<<gA + gB, 256, 0, stream>>>(
      rowT, csrT, lsA, ldA, xsA, out_t, NT,
      rowH, csrH, lsB, ldB, xsB, out_h, NH, bias, gA);
}

// Round 5
// 235.685 us; speedup vs baseline: 1.0930x; 1.0930x over previous
//
#include <hip/hip_runtime.h>
#include <hip/hip_bf16.h>
#include <math.h>

#define HC 64
#define DD 128
#define BSH 7       // bucket = 128 consecutive ids
#define BW  128
#define KMAX 512    // max buckets; ids must fit 16 bits (N <= 65536)
#define CHUNK 4096  // edges per partition workgroup
#define CAP 8192    // LDS sort capacity in bucket_csr (entries)
#define CAPB 6144   // padded per-bucket capacity in part arrays (avg 4224, +13 sigma safe)

typedef __attribute__((ext_vector_type(8))) short bf16x8;
typedef __attribute__((ext_vector_type(4))) float f32x4;

// round-to-nearest-even f32 -> bf16 bits (inputs finite)
__device__ __forceinline__ unsigned short f2bf(float f) {
  unsigned u = __float_as_uint(f);
  return (unsigned short)((u + 0x7fffu + ((u >> 16) & 1u)) >> 16);
}

// ---------------- build folded B matrix [80][128] bf16 ----------------
// cols (rows of Bt) 0..63 : Wsrc^T
// 64: sum_c Wsrc[k][ 0+c]*att_src[ 0+c]*LOG2E   (ls head0)
// 65: sum_c Wsrc[k][32+c]*att_src[32+c]*LOG2E   (ls head1)
// 66: sum_c Wdst[k][ 0+c]*att_dst[ 0+c]*LOG2E   (ld head0)
// 67: sum_c Wdst[k][32+c]*att_dst[32+c]*LOG2E   (ld head1)
// 68..79: zero pad (5 MFMA col-tiles of 16)
__global__ __launch_bounds__(128) void build_bt(
    const float* __restrict__ Wsrc, const float* __restrict__ Wdst,
    const float* __restrict__ att_src, const float* __restrict__ att_dst,
    unsigned short* __restrict__ Bt)
{
  int j = blockIdx.x;      // 0..79
  int k = threadIdx.x;     // 0..127
  const float LOG2E = 1.44269504f;
  float v = 0.f;
  if (j < 64) {
    v = Wsrc[k * HC + j];
  } else if (j < 68) {
    int hh = j - 64;
    const float* W = (hh < 2) ? Wsrc : Wdst;
    const float* a = (hh < 2) ? att_src : att_dst;
    int h = hh & 1;
    float s = 0.f;
    for (int c = 0; c < 32; ++c)
      s = fmaf(W[k * HC + h * 32 + c], a[h * 32 + c], s);
    v = s * LOG2E;
  }
  Bt[j * DD + k] = f2bf(v);
}

// ---------------- node transform via MFMA (both graphs, one grid) ------
// one wave = 16 nodes. A = elu(x) split hi/lo bf16 (error ~= W rounding only).
__global__ __launch_bounds__(256) void node_mfma(
    const float* __restrict__ xH, const float* __restrict__ xT,
    const unsigned short* __restrict__ Bt,
    __hip_bfloat16* __restrict__ xsH, __hip_bfloat16* __restrict__ xsT,
    float* __restrict__ lsH, float* __restrict__ ldH,
    float* __restrict__ lsT, float* __restrict__ ldT,
    int NH, int NT, int blocksH)
{
  const float* x; __hip_bfloat16* xs; float* logit_s; float* logit_d; int N, blk;
  if ((int)blockIdx.x < blocksH) { x = xH; xs = xsH; logit_s = lsH; logit_d = ldH; N = NH; blk = blockIdx.x; }
  else { x = xT; xs = xsT; logit_s = lsT; logit_d = ldT; N = NT; blk = blockIdx.x - blocksH; }

  int tid  = threadIdx.x;
  int wid  = tid >> 6;
  int lane = tid & 63;
  int m    = lane & 15;          // A row / D col index
  int kg   = lane >> 4;          // k-group 0..3
  int nbase = (blk * 4 + wid) * 16;
  if (nbase >= N) return;
  int nrow = nbase + m;
  int nclamp = (nrow < N) ? nrow : (N - 1);

  // ---- load A (4 k-tiles x 8 f32), elu, hi/lo bf16 split ----
  bf16x8 ahi[4], alo[4];
  const float* xrow = x + (size_t)nclamp * DD + kg * 8;
  #pragma unroll
  for (int kt = 0; kt < 4; ++kt) {
    float4 v0 = *(const float4*)(xrow + kt * 32);
    float4 v1 = *(const float4*)(xrow + kt * 32 + 4);
    float vv[8] = {v0.x, v0.y, v0.z, v0.w, v1.x, v1.y, v1.z, v1.w};
    #pragma unroll
    for (int i = 0; i < 8; ++i) {
      float v = vv[i];
      v = (v > 0.f) ? v : (exp2f(v * 1.44269504f) - 1.f);   // elu
      unsigned hb = __float_as_uint(v) & 0xffff0000u;       // truncate -> hi
      ahi[kt][i] = (short)(hb >> 16);
      alo[kt][i] = (short)f2bf(v - __uint_as_float(hb));    // exact residual, RNE
    }
  }

  // ---- MFMA: 5 col-tiles x 4 k-tiles x (hi+lo) ----
  f32x4 acc[5];
  #pragma unroll
  for (int ct = 0; ct < 5; ++ct) acc[ct] = (f32x4){0.f, 0.f, 0.f, 0.f};
  const unsigned short* bbase = Bt + m * DD + kg * 8;   // + ct*16*DD + kt*32
  #pragma unroll
  for (int ct = 0; ct < 5; ++ct) {
    #pragma unroll
    for (int kt = 0; kt < 4; ++kt) {
      bf16x8 b = *(const bf16x8*)(bbase + ct * 16 * DD + kt * 32);
      acc[ct] = __builtin_amdgcn_mfma_f32_16x16x32_bf16(ahi[kt], b, acc[ct], 0, 0, 0);
      acc[ct] = __builtin_amdgcn_mfma_f32_16x16x32_bf16(alo[kt], b, acc[ct], 0, 0, 0);
    }
  }

  // ---- epilogue ----
  int r0 = kg * 4;
  unsigned short* xsu = (unsigned short*)xs;
  #pragma unroll
  for (int ct = 0; ct < 4; ++ct) {
    #pragma unroll
    for (int r = 0; r < 4; ++r) {
      int n = nbase + r0 + r;
      if (n < N) xsu[(size_t)n * HC + ct * 16 + m] = f2bf(acc[ct][r]);
    }
  }
  if (m < 4) {
    float* dst = (m < 2) ? logit_s : logit_d;
    int h = m & 1;
    #pragma unroll
    for (int r = 0; r < 4; ++r) {
      int n = nbase + r0 + r;
      if (n < N) dst[n * 2 + h] = acc[4][r];
    }
  }
}

// ---------------- counting sort (atomic bucket reservation) ----------------
// partition into bucket-PADDED segments. word = other | (key << 16);
// bucket recovered as w >> (16+BSH). Chunk reserves its per-bucket spans
// via device-scope atomicAdd on gcur (no pre-histogram pass needed).
__global__ __launch_bounds__(256) void partition_atomic(
    const int* __restrict__ src, const int* __restrict__ dst, int E, int NL,
    int* __restrict__ gcurA, int* __restrict__ gcurB,
    unsigned int* __restrict__ partA, unsigned int* __restrict__ partB,
    int KA, int KB)
{
  __shared__ unsigned int stage[CHUNK];  // 16 KB
  __shared__ int lcnt[KMAX];
  __shared__ int lbase[KMAX];
  __shared__ int lcur[KMAX];
  __shared__ int gbase[KMAX];
  int tid = threadIdx.x, bid = blockIdx.x;
  int pass = blockIdx.y;
  const int K = pass ? KB : KA;
  int* gcur = pass ? gcurB : gcurA;
  unsigned int* out = pass ? partB : partA;

  int base = bid * CHUNK;
  int E2 = E + NL;
  int lim = base + CHUNK < E2 ? base + CHUNK : E2;
  int cnt = lim - base;

  for (int i = tid; i < K; i += 256) lcnt[i] = 0;
  __syncthreads();
  for (int i = base + tid; i < lim; i += 256) {
    int s, d;
    if (i < E) { s = src[i]; d = dst[i]; } else { s = d = i - E; }
    int key = pass ? s : d;
    atomicAdd(&lcnt[key >> BSH], 1);
  }
  __syncthreads();
  if (tid < 64) {                      // wave-0 exclusive scan over K counts
    int carry = 0;
    for (int c0 = 0; c0 < K; c0 += 64) {
      int c = c0 + tid;
      int v = (c < K) ? lcnt[c] : 0;
      int inc = v;
      #pragma unroll
      for (int o = 1; o < 64; o <<= 1) {
        int u = __shfl_up(inc, o, 64);
        if (tid >= o) inc += u;
      }
      if (c < K) lbase[c] = inc - v + carry;
      carry += __shfl(inc, 63, 64);
    }
  }
  __syncthreads();
  for (int k = tid; k < K; k += 256) {
    lcur[k] = lbase[k];
    gbase[k] = atomicAdd(&gcur[k], lcnt[k]);   // reserve span in bucket k
  }
  __syncthreads();
  for (int i = base + tid; i < lim; i += 256) {
    int s, d;
    if (i < E) { s = src[i]; d = dst[i]; } else { s = d = i - E; }
    int key = pass ? s : d;
    int val = pass ? d : s;
    int pos = atomicAdd(&lcur[key >> BSH], 1);
    stage[pos] = (unsigned int)val | ((unsigned int)key << 16);
  }
  __syncthreads();
  for (int i = tid; i < cnt; i += 256) {
    unsigned int wv = stage[i];
    int k = wv >> (16 + BSH);
    out[(size_t)k * CAPB + gbase[k] + (i - lbase[k])] = wv;
  }
}

// exclusive scan of final bucket counts -> compact csr offsets
__global__ __launch_bounds__(1024) void scan_offsets(
    const int* __restrict__ gcurA, const int* __restrict__ gcurB,
    int KA, int KB, int E2,
    int* __restrict__ offA, int* __restrict__ offB)
{
  __shared__ int buf[1024];
  int t = threadIdx.x;
  int v = (t < KA) ? gcurA[t] : 0;
  buf[t] = v; __syncthreads();
  #pragma unroll
  for (int off = 1; off < 1024; off <<= 1) {
    int u = (t >= off) ? buf[t - off] : 0;
    __syncthreads(); buf[t] += u; __syncthreads();
  }
  if (t < KA) offA[t] = buf[t] - v;
  if (t == 0) offA[KA] = E2;
  __syncthreads();
  int v2 = (t < KB) ? gcurB[t] : 0;
  buf[t] = v2; __syncthreads();
  #pragma unroll
  for (int off = 1; off < 1024; off <<= 1) {
    int u = (t >= off) ? buf[t - off] : 0;
    __syncthreads(); buf[t] += u; __syncthreads();
  }
  if (t < KB) offB[t] = buf[t] - v2;
  if (t == 0) offB[KB] = E2;
}

// per-bucket key-sort in LDS -> compact csr (coalesced write) + row pointers
__global__ __launch_bounds__(256) void bucket_csr3(
    const unsigned int* __restrict__ partA, const int* __restrict__ cntA,
    const int* __restrict__ offA, int KA, int NA,
    const unsigned int* __restrict__ partB, const int* __restrict__ cntB,
    const int* __restrict__ offB, int KB, int NB,
    int E2, int* __restrict__ csrA, int* __restrict__ rowA,
    int* __restrict__ csrB, int* __restrict__ rowB)
{
  __shared__ int sbuf[CAP];        // 32 KB
  __shared__ int hist[BW + 1];
  __shared__ int cur[BW];
  const unsigned int* part; const int* off; const int* cntp;
  int* csr; int* row; int k, K, N;
  if ((int)blockIdx.x < KA) { k = blockIdx.x; part = partA; off = offA; cntp = cntA; csr = csrA; row = rowA; K = KA; N = NA; }
  else { k = blockIdx.x - KA; part = partB; off = offB; cntp = cntB; csr = csrB; row = rowB; K = KB; N = NB; }
  int tid = threadIdx.x;
  int beg = off[k];                    // compact output base
  int cnt = cntp[k];
  size_t kbase = (size_t)k * CAPB;     // padded input base
  int d0 = k << BSH;
  int width = (BW < N - d0) ? BW : (N - d0);

  for (int i = tid; i <= BW; i += 256) hist[i] = 0;
  __syncthreads();
  for (int i = tid; i < cnt; i += 256)
    atomicAdd(&hist[(part[kbase + i] >> 16) & (BW - 1)], 1);
  __syncthreads();
  if (tid == 0) {
    int run = 0;
    for (int j = 0; j < width; ++j) { int c = hist[j]; hist[j] = run; run += c; }
    hist[width] = run;
  }
  __syncthreads();
  if (tid < width) { cur[tid] = hist[tid]; row[d0 + tid] = beg + hist[tid]; }
  if (k == K - 1 && tid == 0) row[N] = E2;
  __syncthreads();
  if (cnt <= CAP) {
    for (int i = tid; i < cnt; i += 256) {
      unsigned int wv = part[kbase + i];
      int pos = atomicAdd(&cur[(wv >> 16) & (BW - 1)], 1);
      sbuf[pos] = wv & 0xFFFF;
    }
    __syncthreads();
    for (int i = tid; i < cnt; i += 256) csr[beg + i] = sbuf[i];
  } else {
    for (int i = tid; i < cnt; i += 256) {   // fallback, never for uniform data
      unsigned int wv = part[kbase + i];
      int pos = atomicAdd(&cur[(wv >> 16) & (BW - 1)], 1);
      csr[beg + pos] = wv & 0xFFFF;
    }
  }
}

// ---------------- message stage ----------------
__device__ __forceinline__ float lrelu_clamp(float a) {
  a = (a > 0.f) ? a : 0.2f * a;
  return fminf(a, 43.f);
}

// csr_message5: half-wave per dst (2 dsts/wave), 2 channels per lane.
// Per 32-edge tile: lane l31 computes edge l31's (sv,e0,e1) once, deposits
// into bank-staggered per-wave LDS arrays (word bases mod 32 = 0/8/16/24
// so quad reads are bank-disjoint). Inner loop reads ONE int4 sv-quad +
// ONE float4 w-quad per 4 edges (ds_read_b128, conflict-free broadcast),
// statically indexed -> 4x fewer LDS instructions, zero conflicts.
// All 32 slots are always written (invalid lanes write 0s) so whole-quad
// processing past tc is exact (adds w=0 terms).
__global__ __launch_bounds__(256) void csr_message5(
    const int* __restrict__ rowA, const int* __restrict__ csrA,
    const float* __restrict__ lsA, const float* __restrict__ ldA,
    const __hip_bfloat16* __restrict__ xsA, float* __restrict__ outA, int NdA,
    const int* __restrict__ rowB, const int* __restrict__ csrB,
    const float* __restrict__ lsB, const float* __restrict__ ldB,
    const __hip_bfloat16* __restrict__ xsB, float* __restrict__ outB, int NdB,
    const float* __restrict__ bias, int blocksA)
{
  const int* row; const int* csr_src; const float* logit_s; const float* logit_d;
  const __hip_bfloat16* xs; float* out; int Nd, blk;
  if ((int)blockIdx.x < blocksA) { row = rowA; csr_src = csrA; logit_s = lsA; logit_d = ldA; xs = xsA; out = outA; Nd = NdA; blk = blockIdx.x; }
  else { row = rowB; csr_src = csrB; logit_s = lsB; logit_d = ldB; xs = xsB; out = outB; Nd = NdB; blk = blockIdx.x - blocksA; }

  // per-wave strip: 232 words. word offsets (base mod 32 in parens):
  //   sv0 @   0 (0)   sv1 @  40 (8)
  //   w00 @  80 (16)  w01 @ 120 (24)   [half0: e0, e1]
  //   w10 @ 160 (0)   w11 @ 200 (8)    [half1: e0, e1]
  __shared__ int lds[4 * 232];     // 3712 B
  int tid  = threadIdx.x;
  int wid  = tid >> 6;
  int lane = tid & 63;
  int l31  = lane & 31;
  int half = lane >> 5;
  int head = l31 >> 4;             // channel group -> attention head

  int* L = &lds[wid * 232];
  float* Lf = (float*)L;
  int sv_w = (half ? 40 : 0) + l31;
  int w0_w = (half ? 160 : 80) + l31;
  int w1_w = (half ? 200 : 120) + l31;
  const int4*   svq = (const int4*)  (L  + (half ? 40 : 0));
  const float4* wq  = (const float4*)(Lf + (half ? (head ? 200 : 160)
                                                 : (head ? 120 : 80)));
  const unsigned* xs2 = (const unsigned*)xs;     // bf16 pair per dword
  const float2* ls2 = (const float2*)logit_s;

  int d = blk * 8 + (wid << 1) + half;
  int beg = 0, end = 0;
  float2 ld2 = {0.f, 0.f};
  if (d < Nd) {
    beg = row[d]; end = row[d + 1];
    ld2 = ((const float2*)logit_d)[d];
  }

  int nt = ((end - beg) + 31) >> 5;
  nt = max(nt, __shfl_xor(nt, 32, 64));      // wave-uniform tile count

  float2 accA = {0.f, 0.f}, accB = {0.f, 0.f};
  float s0 = 0.f, s1 = 0.f;
  int myPos = beg;

#define STEP(SV, W, ACC) {                                         \
    unsigned xv = xs2[(SV) * 32 + l31];                            \
    ACC.x = fmaf((W), __uint_as_float(xv << 16), ACC.x);           \
    ACC.y = fmaf((W), __uint_as_float(xv & 0xffff0000u), ACC.y);   \
  }

  for (int tile = 0; tile < nt; ++tile, myPos += 32) {
    int tc = end - myPos; tc = tc < 0 ? 0 : (tc > 32 ? 32 : tc);
    int sv = 0; float e0 = 0.f, e1 = 0.f;
    if (l31 < tc) {
      sv = csr_src[myPos + l31];
      float2 l2 = ls2[sv];
      e0 = exp2f(lrelu_clamp(l2.x + ld2.x));
      e1 = exp2f(lrelu_clamp(l2.y + ld2.y));
    }
    s0 += e0; s1 += e1;
    L[sv_w]       = sv;
    Lf[w0_w]      = e0;
    Lf[w1_w]      = e1;
    // same-wave cross-lane LDS RAW: DS in-order per wave; this asm is a
    // compiler barrier (no reordering) + drains the writes
    asm volatile("s_waitcnt lgkmcnt(0)" ::: "memory");
    int tcmax = max(tc, __shfl_xor(tc, 32, 64));
    int nq = (tcmax + 3) >> 2;
    for (int q = 0; q < nq; ++q) {
      int4   s4 = svq[q];
      float4 w4 = wq[q];
      STEP(s4.x, w4.x, accA)
      STEP(s4.y, w4.y, accB)
      STEP(s4.z, w4.z, accA)
      STEP(s4.w, w4.w, accB)
    }
  }
#undef STEP

  // denominators: reduce within each 32-lane half
  #pragma unroll
  for (int off = 16; off > 0; off >>= 1) {
    s0 += __shfl_xor(s0, off, 64);
    s1 += __shfl_xor(s1, off, 64);
  }
  float sD = (l31 & 16) ? s1 : s0;
  float inv = 1.f / (sD + 1e-16f);

  if (d < Nd) {
    float2 b2 = ((const float2*)bias)[l31];
    float2 o;
    o.x = (accA.x + accB.x) * inv + b2.x;
    o.y = (accA.y + accB.y) * inv + b2.y;
    ((float2*)out)[(size_t)d * 32 + l31] = o;
  }
}

extern "C" void kernel_launch(void* const* d_in, const int* in_sizes, int n_in,
                              void* d_out, int out_size, void* d_ws, size_t ws_size,
                              hipStream_t stream)
{
  const float* h_x   = (const float*)d_in[0];
  const float* t_x   = (const float*)d_in[1];
  const int*   edge  = (const int*)d_in[2];
  const float* W_src = (const float*)d_in[3];
  const float* W_dst = (const float*)d_in[4];
  const float* att_s = (const float*)d_in[5];
  const float* att_d = (const float*)d_in[6];
  const float* bias  = (const float*)d_in[7];

  int NH = in_sizes[0] / DD;
  int NT = in_sizes[1] / DD;
  int E  = in_sizes[2] / 2;
  int NL = (NH < NT) ? NH : NT;
  int E2 = E + NL;
  const int* srcA = edge;       // row 0 (h index)
  const int* dstA = edge + E;   // row 1 (t index)

  int KA = (NT + BW - 1) >> BSH;   // pass A buckets (over t / dst)
  int KB = (NH + BW - 1) >> BSH;   // pass B buckets (over h / src)
  int B  = (E2 + CHUNK - 1) / CHUNK;

  char* w = (char*)d_ws;
  size_t used = 0;
  auto alloc = [&](size_t bytes) {
    char* p = w + used; used = (used + bytes + 255) & ~(size_t)255; return p;
  };
  __hip_bfloat16* xsA = (__hip_bfloat16*)alloc((size_t)NH * HC * 2);
  __hip_bfloat16* xsB = (__hip_bfloat16*)alloc((size_t)NT * HC * 2);
  float* lsA  = (float*)alloc((size_t)NH * 2 * 4);
  float* ldB  = (float*)alloc((size_t)NH * 2 * 4);
  float* lsB  = (float*)alloc((size_t)NT * 2 * 4);
  float* ldA  = (float*)alloc((size_t)NT * 2 * 4);
  int* gcur   = (int*)alloc((size_t)(KA + KB) * 4);      // bucket cursors (zeroed)
  int* gcurA  = gcur;
  int* gcurB  = gcur + KA;
  int* offA   = (int*)alloc((size_t)(KA + 1) * 4);
  int* offB   = (int*)alloc((size_t)(KB + 1) * 4);
  int* rowT   = (int*)alloc((size_t)(NT + 1) * 4);
  int* rowH   = (int*)alloc((size_t)(NH + 1) * 4);
  unsigned int* partA = (unsigned int*)alloc((size_t)KA * CAPB * 4);  // padded
  unsigned int* partB = (unsigned int*)alloc((size_t)KB * CAPB * 4);  // padded
  int* csrT   = (int*)alloc((size_t)E2 * 4);
  int* csrH   = (int*)alloc((size_t)E2 * 4);
  unsigned short* Bt = (unsigned short*)alloc((size_t)80 * DD * 2);

  float* out   = (float*)d_out;              // (h_rep [NH,64], t_rep [NT,64])
  float* out_h = out;
  float* out_t = out + (size_t)NH * HC;

  build_bt<<<80, 128, 0, stream>>>(W_src, W_dst, att_s, att_d, Bt);

  int bH = (NH + 63) / 64, bT = (NT + 63) / 64;
  node_mfma<<<bH + bT, 256, 0, stream>>>(
      h_x, t_x, Bt, xsA, xsB, lsA, ldB, lsB, ldA, NH, NT, bH);

  hipMemsetAsync(gcur, 0, (size_t)(KA + KB) * 4, stream);
  partition_atomic<<<dim3(B, 2), 256, 0, stream>>>(
      srcA, dstA, E, NL, gcurA, gcurB, partA, partB, KA, KB);
  scan_offsets<<<1, 1024, 0, stream>>>(gcurA, gcurB, KA, KB, E2, offA, offB);
  bucket_csr3<<<KA + KB, 256, 0, stream>>>(
      partA, gcurA, offA, KA, NT, partB, gcurB, offB, KB, NH,
      E2, csrT, rowT, csrH, rowH);

  // pass A: src=h, dst=t -> t_rep ; pass B: src=t, dst=h -> h_rep
  // 8 dsts per block (4 waves x 2 dsts/wave)
  int gA = (NT + 7) / 8, gB = (NH + 7) / 8;
  csr_message5<<<gA + gB, 256, 0, stream>>>(
      rowT, csrT, lsA, ldA, xsA, out_t, NT,
      rowH, csrH, lsB, ldB, xsB, out_h, NH, bias, gA);
}

// Round 6
// 221.291 us; speedup vs baseline: 1.1641x; 1.0650x over previous
//
#include <hip/hip_runtime.h>
#include <hip/hip_bf16.h>
#include <math.h>

#define HC 64
#define DD 128
#define BSH 7       // bucket = 128 consecutive ids
#define BW  128
#define KMAX 512    // max buckets; ids must fit 16 bits (N <= 65536)
#define CHUNK 4096  // edges per partition chunk
#define CAP 8192    // LDS sort capacity in bucket_csr (entries)
#define CAPB 6144   // padded per-bucket capacity (avg 4224, +29 sigma safe)

typedef __attribute__((ext_vector_type(8))) short bf16x8;
typedef __attribute__((ext_vector_type(4))) float f32x4;

// round-to-nearest-even f32 -> bf16 bits (inputs finite)
__device__ __forceinline__ unsigned short f2bf(float f) {
  unsigned u = __float_as_uint(f);
  return (unsigned short)((u + 0x7fffu + ((u >> 16) & 1u)) >> 16);
}

// ---------------- build folded B matrix [80][128] bf16 + zero cursors ----
// cols (rows of Bt) 0..63 : Wsrc^T
// 64/65: Wsrc@att_src head0/1 (*LOG2E)   66/67: Wdst@att_dst head0/1 (*LOG2E)
// 68..79: zero pad. Block 0 also zeroes the gcur bucket cursors (stream
// order guarantees completion before fused_front's partition blocks).
__global__ __launch_bounds__(128) void build_bt(
    const float* __restrict__ Wsrc, const float* __restrict__ Wdst,
    const float* __restrict__ att_src, const float* __restrict__ att_dst,
    unsigned short* __restrict__ Bt, int* __restrict__ gcur, int KK)
{
  int j = blockIdx.x;      // 0..79
  int k = threadIdx.x;     // 0..127
  const float LOG2E = 1.44269504f;
  float v = 0.f;
  if (j < 64) {
    v = Wsrc[k * HC + j];
  } else if (j < 68) {
    int hh = j - 64;
    const float* W = (hh < 2) ? Wsrc : Wdst;
    const float* a = (hh < 2) ? att_src : att_dst;
    int h = hh & 1;
    float s = 0.f;
    for (int c = 0; c < 32; ++c)
      s = fmaf(W[k * HC + h * 32 + c], a[h * 32 + c], s);
    v = s * LOG2E;
  }
  Bt[j * DD + k] = f2bf(v);
  if (j == 0) {
    for (int i = k; i < KK; i += 128) gcur[i] = 0;
  }
}

// ---------------- fused front: node transform (MFMA) + edge partition ----
// Blocks [0, nodeB): node transform, 8 waves x 16 nodes = 128 nodes/block.
// Blocks [nodeB, nodeB+B): partition. Edges read ONCE into LDS raw
// (s|d<<16, both ids < 65536), then BOTH bucket passes (dst-key -> partA,
// src-key -> partB) count/scan/place from LDS. Per-bucket spans reserved
// via device-scope atomicAdd on gcur (no pre-histogram kernel).
__global__ __launch_bounds__(512) void fused_front(
    const float* __restrict__ xH, const float* __restrict__ xT,
    const unsigned short* __restrict__ Bt,
    __hip_bfloat16* __restrict__ xsH, __hip_bfloat16* __restrict__ xsT,
    float* __restrict__ lsH, float* __restrict__ ldH,
    float* __restrict__ lsT, float* __restrict__ ldT,
    int NH, int NT, int blocksH, int nodeB,
    const int* __restrict__ src, const int* __restrict__ dst, int E, int NL,
    int* __restrict__ gcurA, int* __restrict__ gcurB,
    unsigned int* __restrict__ partA, unsigned int* __restrict__ partB,
    int KA, int KB)
{
  __shared__ unsigned int raw[CHUNK];    // 16 KB  (s | d<<16)
  __shared__ unsigned int stage[CHUNK];  // 16 KB
  __shared__ int lcnt[KMAX];             // 2 KB
  __shared__ int lbase[KMAX];            // 2 KB
  __shared__ int lcur[KMAX];             // 2 KB
  __shared__ int gbase[KMAX];            // 2 KB

  int tid = threadIdx.x;

  if ((int)blockIdx.x < nodeB) {
    // ================= node transform via MFMA =================
    // one wave = 16 nodes. A = elu(x) split hi/lo bf16.
    const float* x; __hip_bfloat16* xs; float* logit_s; float* logit_d; int N, blk;
    if ((int)blockIdx.x < blocksH) { x = xH; xs = xsH; logit_s = lsH; logit_d = ldH; N = NH; blk = blockIdx.x; }
    else { x = xT; xs = xsT; logit_s = lsT; logit_d = ldT; N = NT; blk = blockIdx.x - blocksH; }

    int wid  = tid >> 6;          // 0..7
    int lane = tid & 63;
    int m    = lane & 15;         // A row / D col index
    int kg   = lane >> 4;         // k-group 0..3
    int nbase = (blk * 8 + wid) * 16;
    if (nbase >= N) return;
    int nrow = nbase + m;
    int nclamp = (nrow < N) ? nrow : (N - 1);

    // ---- load A (4 k-tiles x 8 f32), elu, hi/lo bf16 split ----
    bf16x8 ahi[4], alo[4];
    const float* xrow = x + (size_t)nclamp * DD + kg * 8;
    #pragma unroll
    for (int kt = 0; kt < 4; ++kt) {
      float4 v0 = *(const float4*)(xrow + kt * 32);
      float4 v1 = *(const float4*)(xrow + kt * 32 + 4);
      float vv[8] = {v0.x, v0.y, v0.z, v0.w, v1.x, v1.y, v1.z, v1.w};
      #pragma unroll
      for (int i = 0; i < 8; ++i) {
        float v = vv[i];
        v = (v > 0.f) ? v : (exp2f(v * 1.44269504f) - 1.f);   // elu
        unsigned hb = __float_as_uint(v) & 0xffff0000u;       // truncate -> hi
        ahi[kt][i] = (short)(hb >> 16);
        alo[kt][i] = (short)f2bf(v - __uint_as_float(hb));    // exact residual, RNE
      }
    }

    // ---- MFMA: 5 col-tiles x 4 k-tiles x (hi+lo) ----
    f32x4 acc[5];
    #pragma unroll
    for (int ct = 0; ct < 5; ++ct) acc[ct] = (f32x4){0.f, 0.f, 0.f, 0.f};
    const unsigned short* bbase = Bt + m * DD + kg * 8;
    #pragma unroll
    for (int ct = 0; ct < 5; ++ct) {
      #pragma unroll
      for (int kt = 0; kt < 4; ++kt) {
        bf16x8 b = *(const bf16x8*)(bbase + ct * 16 * DD + kt * 32);
        acc[ct] = __builtin_amdgcn_mfma_f32_16x16x32_bf16(ahi[kt], b, acc[ct], 0, 0, 0);
        acc[ct] = __builtin_amdgcn_mfma_f32_16x16x32_bf16(alo[kt], b, acc[ct], 0, 0, 0);
      }
    }

    // ---- epilogue ----
    int r0 = kg * 4;
    unsigned short* xsu = (unsigned short*)xs;
    #pragma unroll
    for (int ct = 0; ct < 4; ++ct) {
      #pragma unroll
      for (int r = 0; r < 4; ++r) {
        int n = nbase + r0 + r;
        if (n < N) xsu[(size_t)n * HC + ct * 16 + m] = f2bf(acc[ct][r]);
      }
    }
    if (m < 4) {
      float* dstp = (m < 2) ? logit_s : logit_d;
      int h = m & 1;
      #pragma unroll
      for (int r = 0; r < 4; ++r) {
        int n = nbase + r0 + r;
        if (n < N) dstp[n * 2 + h] = acc[4][r];
      }
    }
    return;
  }

  // ================= partition (both passes, single edge read) =========
  int bid = blockIdx.x - nodeB;
  int base = bid * CHUNK;
  int E2 = E + NL;
  int lim = base + CHUNK < E2 ? base + CHUNK : E2;
  int cnt = lim - base;

  for (int i = base + tid; i < lim; i += 512) {
    unsigned s, d;
    if (i < E) { s = (unsigned)src[i]; d = (unsigned)dst[i]; }
    else       { s = d = (unsigned)(i - E); }
    raw[i - base] = s | (d << 16);
  }
  __syncthreads();

  for (int p = 0; p < 2; ++p) {
    const int K = p ? KB : KA;
    int* gcur = p ? gcurB : gcurA;
    unsigned int* outp = p ? partB : partA;

    for (int k2 = tid; k2 < K; k2 += 512) lcnt[k2] = 0;
    __syncthreads();
    for (int i = tid; i < cnt; i += 512) {
      unsigned w = raw[i];
      unsigned key = p ? (w & 0xffffu) : (w >> 16);
      atomicAdd(&lcnt[key >> BSH], 1);
    }
    __syncthreads();
    if (tid < 64) {                      // wave-0 exclusive scan over K counts
      int carry = 0;
      for (int c0 = 0; c0 < K; c0 += 64) {
        int c = c0 + tid;
        int v = (c < K) ? lcnt[c] : 0;
        int inc = v;
        #pragma unroll
        for (int o = 1; o < 64; o <<= 1) {
          int u = __shfl_up(inc, o, 64);
          if (tid >= o) inc += u;
        }
        if (c < K) lbase[c] = inc - v + carry;
        carry += __shfl(inc, 63, 64);
      }
    }
    __syncthreads();
    for (int k2 = tid; k2 < K; k2 += 512) {
      lcur[k2] = lbase[k2];
      gbase[k2] = atomicAdd(&gcur[k2], lcnt[k2]);   // reserve span in bucket
    }
    __syncthreads();
    for (int i = tid; i < cnt; i += 512) {
      unsigned w = raw[i];
      unsigned key = p ? (w & 0xffffu) : (w >> 16);
      unsigned val = p ? (w >> 16) : (w & 0xffffu);
      int pos = atomicAdd(&lcur[key >> BSH], 1);
      stage[pos] = val | (key << 16);
    }
    __syncthreads();
    for (int i = tid; i < cnt; i += 512) {
      unsigned wv = stage[i];
      int kk = wv >> (16 + BSH);
      outp[(size_t)kk * CAPB + gbase[kk] + (i - lbase[kk])] = wv;
    }
    __syncthreads();    // stage/lcnt reused by next pass
  }
}

// per-bucket key-sort in LDS -> compact csr + row pointers; offset computed
// in-block (prefix over cnt[0..k)) - no separate scan dispatch.
__global__ __launch_bounds__(256) void bucket_csr4(
    const unsigned int* __restrict__ partA, const int* __restrict__ cntA,
    int KA, int NA,
    const unsigned int* __restrict__ partB, const int* __restrict__ cntB,
    int KB, int NB,
    int E2, int* __restrict__ csrA, int* __restrict__ rowA,
    int* __restrict__ csrB, int* __restrict__ rowB)
{
  __shared__ int sbuf[CAP];        // 32 KB
  __shared__ int hist[BW + 1];
  __shared__ int cur[BW];
  __shared__ int red[256];
  const unsigned int* part; const int* cntp;
  int* csr; int* row; int k, K, N;
  if ((int)blockIdx.x < KA) { k = blockIdx.x; part = partA; cntp = cntA; csr = csrA; row = rowA; K = KA; N = NA; }
  else { k = blockIdx.x - KA; part = partB; cntp = cntB; csr = csrB; row = rowB; K = KB; N = NB; }
  int tid = threadIdx.x;

  // beg = exclusive prefix of bucket counts
  int psum = 0;
  for (int j = tid; j < k; j += 256) psum += cntp[j];
  red[tid] = psum; __syncthreads();
  for (int s = 128; s > 0; s >>= 1) {
    if (tid < s) red[tid] += red[tid + s];
    __syncthreads();
  }
  int beg = red[0];
  int cnt = cntp[k];
  size_t kbase = (size_t)k * CAPB;     // padded input base
  int d0 = k << BSH;
  int width = (BW < N - d0) ? BW : (N - d0);

  for (int i = tid; i <= BW; i += 256) hist[i] = 0;
  __syncthreads();
  for (int i = tid; i < cnt; i += 256)
    atomicAdd(&hist[(part[kbase + i] >> 16) & (BW - 1)], 1);
  __syncthreads();
  if (tid == 0) {
    int run = 0;
    for (int j = 0; j < width; ++j) { int c = hist[j]; hist[j] = run; run += c; }
    hist[width] = run;
  }
  __syncthreads();
  if (tid < width) { cur[tid] = hist[tid]; row[d0 + tid] = beg + hist[tid]; }
  if (k == K - 1 && tid == 0) row[N] = E2;
  __syncthreads();
  if (cnt <= CAP) {
    for (int i = tid; i < cnt; i += 256) {
      unsigned int wv = part[kbase + i];
      int pos = atomicAdd(&cur[(wv >> 16) & (BW - 1)], 1);
      sbuf[pos] = wv & 0xFFFF;
    }
    __syncthreads();
    for (int i = tid; i < cnt; i += 256) csr[beg + i] = sbuf[i];
  } else {
    for (int i = tid; i < cnt; i += 256) {   // fallback, never for uniform data
      unsigned int wv = part[kbase + i];
      int pos = atomicAdd(&cur[(wv >> 16) & (BW - 1)], 1);
      csr[beg + pos] = wv & 0xFFFF;
    }
  }
}

// ---------------- message stage ----------------
__device__ __forceinline__ float lrelu_clamp(float a) {
  a = (a > 0.f) ? a : 0.2f * a;
  return fminf(a, 43.f);
}

// csr_message5: half-wave per dst (2 dsts/wave), 2 channels per lane.
// Bank-staggered per-wave LDS arrays; quad ds_read_b128 broadcasts,
// zero conflicts; all 32 slots always written so over-run adds w=0 terms.
__global__ __launch_bounds__(256) void csr_message5(
    const int* __restrict__ rowA, const int* __restrict__ csrA,
    const float* __restrict__ lsA, const float* __restrict__ ldA,
    const __hip_bfloat16* __restrict__ xsA, float* __restrict__ outA, int NdA,
    const int* __restrict__ rowB, const int* __restrict__ csrB,
    const float* __restrict__ lsB, const float* __restrict__ ldB,
    const __hip_bfloat16* __restrict__ xsB, float* __restrict__ outB, int NdB,
    const float* __restrict__ bias, int blocksA)
{
  const int* row; const int* csr_src; const float* logit_s; const float* logit_d;
  const __hip_bfloat16* xs; float* out; int Nd, blk;
  if ((int)blockIdx.x < blocksA) { row = rowA; csr_src = csrA; logit_s = lsA; logit_d = ldA; xs = xsA; out = outA; Nd = NdA; blk = blockIdx.x; }
  else { row = rowB; csr_src = csrB; logit_s = lsB; logit_d = ldB; xs = xsB; out = outB; Nd = NdB; blk = blockIdx.x - blocksA; }

  // per-wave strip: 232 words. word offsets (base mod 32 in parens):
  //   sv0 @   0 (0)   sv1 @  40 (8)
  //   w00 @  80 (16)  w01 @ 120 (24)   [half0: e0, e1]
  //   w10 @ 160 (0)   w11 @ 200 (8)    [half1: e0, e1]
  __shared__ int lds[4 * 232];     // 3712 B
  int tid  = threadIdx.x;
  int wid  = tid >> 6;
  int lane = tid & 63;
  int l31  = lane & 31;
  int half = lane >> 5;
  int head = l31 >> 4;             // channel group -> attention head

  int* L = &lds[wid * 232];
  float* Lf = (float*)L;
  int sv_w = (half ? 40 : 0) + l31;
  int w0_w = (half ? 160 : 80) + l31;
  int w1_w = (half ? 200 : 120) + l31;
  const int4*   svq = (const int4*)  (L  + (half ? 40 : 0));
  const float4* wq  = (const float4*)(Lf + (half ? (head ? 200 : 160)
                                                 : (head ? 120 : 80)));
  const unsigned* xs2 = (const unsigned*)xs;     // bf16 pair per dword
  const float2* ls2 = (const float2*)logit_s;

  int d = blk * 8 + (wid << 1) + half;
  int beg = 0, end = 0;
  float2 ld2 = {0.f, 0.f};
  if (d < Nd) {
    beg = row[d]; end = row[d + 1];
    ld2 = ((const float2*)logit_d)[d];
  }

  int nt = ((end - beg) + 31) >> 5;
  nt = max(nt, __shfl_xor(nt, 32, 64));      // wave-uniform tile count

  float2 accA = {0.f, 0.f}, accB = {0.f, 0.f};
  float s0 = 0.f, s1 = 0.f;
  int myPos = beg;

#define STEP(SV, W, ACC) {                                         \
    unsigned xv = xs2[(SV) * 32 + l31];                            \
    ACC.x = fmaf((W), __uint_as_float(xv << 16), ACC.x);           \
    ACC.y = fmaf((W), __uint_as_float(xv & 0xffff0000u), ACC.y);   \
  }

  for (int tile = 0; tile < nt; ++tile, myPos += 32) {
    int tc = end - myPos; tc = tc < 0 ? 0 : (tc > 32 ? 32 : tc);
    int sv = 0; float e0 = 0.f, e1 = 0.f;
    if (l31 < tc) {
      sv = csr_src[myPos + l31];
      float2 l2 = ls2[sv];
      e0 = exp2f(lrelu_clamp(l2.x + ld2.x));
      e1 = exp2f(lrelu_clamp(l2.y + ld2.y));
    }
    s0 += e0; s1 += e1;
    L[sv_w]       = sv;
    Lf[w0_w]      = e0;
    Lf[w1_w]      = e1;
    // same-wave cross-lane LDS RAW: DS in-order per wave; this asm is a
    // compiler barrier (no reordering) + drains the writes
    asm volatile("s_waitcnt lgkmcnt(0)" ::: "memory");
    int tcmax = max(tc, __shfl_xor(tc, 32, 64));
    int nq = (tcmax + 3) >> 2;
    for (int q = 0; q < nq; ++q) {
      int4   s4 = svq[q];
      float4 w4 = wq[q];
      STEP(s4.x, w4.x, accA)
      STEP(s4.y, w4.y, accB)
      STEP(s4.z, w4.z, accA)
      STEP(s4.w, w4.w, accB)
    }
  }
#undef STEP

  // denominators: reduce within each 32-lane half
  #pragma unroll
  for (int off = 16; off > 0; off >>= 1) {
    s0 += __shfl_xor(s0, off, 64);
    s1 += __shfl_xor(s1, off, 64);
  }
  float sD = (l31 & 16) ? s1 : s0;
  float inv = 1.f / (sD + 1e-16f);

  if (d < Nd) {
    float2 b2 = ((const float2*)bias)[l31];
    float2 o;
    o.x = (accA.x + accB.x) * inv + b2.x;
    o.y = (accA.y + accB.y) * inv + b2.y;
    ((float2*)out)[(size_t)d * 32 + l31] = o;
  }
}

extern "C" void kernel_launch(void* const* d_in, const int* in_sizes, int n_in,
                              void* d_out, int out_size, void* d_ws, size_t ws_size,
                              hipStream_t stream)
{
  const float* h_x   = (const float*)d_in[0];
  const float* t_x   = (const float*)d_in[1];
  const int*   edge  = (const int*)d_in[2];
  const float* W_src = (const float*)d_in[3];
  const float* W_dst = (const float*)d_in[4];
  const float* att_s = (const float*)d_in[5];
  const float* att_d = (const float*)d_in[6];
  const float* bias  = (const float*)d_in[7];

  int NH = in_sizes[0] / DD;
  int NT = in_sizes[1] / DD;
  int E  = in_sizes[2] / 2;
  int NL = (NH < NT) ? NH : NT;
  int E2 = E + NL;
  const int* srcA = edge;       // row 0 (h index)
  const int* dstA = edge + E;   // row 1 (t index)

  int KA = (NT + BW - 1) >> BSH;   // pass A buckets (over t / dst)
  int KB = (NH + BW - 1) >> BSH;   // pass B buckets (over h / src)
  int B  = (E2 + CHUNK - 1) / CHUNK;

  char* w = (char*)d_ws;
  size_t used = 0;
  auto alloc = [&](size_t bytes) {
    char* p = w + used; used = (used + bytes + 255) & ~(size_t)255; return p;
  };
  __hip_bfloat16* xsA = (__hip_bfloat16*)alloc((size_t)NH * HC * 2);
  __hip_bfloat16* xsB = (__hip_bfloat16*)alloc((size_t)NT * HC * 2);
  float* lsA  = (float*)alloc((size_t)NH * 2 * 4);
  float* ldB  = (float*)alloc((size_t)NH * 2 * 4);
  float* lsB  = (float*)alloc((size_t)NT * 2 * 4);
  float* ldA  = (float*)alloc((size_t)NT * 2 * 4);
  int* gcur   = (int*)alloc((size_t)(KA + KB) * 4);      // bucket cursors
  int* gcurA  = gcur;
  int* gcurB  = gcur + KA;
  int* rowT   = (int*)alloc((size_t)(NT + 1) * 4);
  int* rowH   = (int*)alloc((size_t)(NH + 1) * 4);
  unsigned int* partA = (unsigned int*)alloc((size_t)KA * CAPB * 4);  // padded
  unsigned int* partB = (unsigned int*)alloc((size_t)KB * CAPB * 4);  // padded
  int* csrT   = (int*)alloc((size_t)E2 * 4);
  int* csrH   = (int*)alloc((size_t)E2 * 4);
  unsigned short* Bt = (unsigned short*)alloc((size_t)80 * DD * 2);

  float* out   = (float*)d_out;              // (h_rep [NH,64], t_rep [NT,64])
  float* out_h = out;
  float* out_t = out + (size_t)NH * HC;

  build_bt<<<80, 128, 0, stream>>>(W_src, W_dst, att_s, att_d, Bt,
                                   gcur, KA + KB);

  int bH = (NH + 127) / 128, bT = (NT + 127) / 128;
  int nodeB = bH + bT;
  fused_front<<<nodeB + B, 512, 0, stream>>>(
      h_x, t_x, Bt, xsA, xsB, lsA, ldB, lsB, ldA, NH, NT, bH, nodeB,
      srcA, dstA, E, NL, gcurA, gcurB, partA, partB, KA, KB);

  bucket_csr4<<<KA + KB, 256, 0, stream>>>(
      partA, gcurA, KA, NT, partB, gcurB, KB, NH,
      E2, csrT, rowT, csrH, rowH);

  // pass A: src=h, dst=t -> t_rep ; pass B: src=t, dst=h -> h_rep
  // 8 dsts per block (4 waves x 2 dsts/wave)
  int gA = (NT + 7) / 8, gB = (NH + 7) / 8;
  csr_message5<<<gA + gB, 256, 0, stream>>>(
      rowT, csrT, lsA, ldA, xsA, out_t, NT,
      rowH, csrH, lsB, ldB, xsB, out_h, NH, bias, gA);
}